// Round 1
// baseline (1111.654 us; speedup 1.0000x reference)
//
#include <hip/hip_runtime.h>

#define D_MODEL 1024
#define SEQ 2048
#define NHEAD 16
#define HDIM 64
#define FF_DIM 4096
#define NTOK 4096  // 2 * 2048

using bf16x8 = __attribute__((ext_vector_type(8))) short;
using f32x4  = __attribute__((ext_vector_type(4))) float;
typedef unsigned short ushort_t;

__device__ __forceinline__ unsigned short f2bu(float f) {
    unsigned int u = __float_as_uint(f);
    unsigned int r = u + 0x7FFFu + ((u >> 16) & 1u);
    return (unsigned short)(r >> 16);
}
__device__ __forceinline__ float b2f(unsigned short u) {
    union { unsigned int i; float f; } x;
    x.i = ((unsigned int)u) << 16;
    return x.f;
}

// ---------------- cast f32 -> bf16 (8 elems / thread) ----------------
__global__ void cast_f32_to_bf16(const float* __restrict__ in, ushort_t* __restrict__ out, int n8) {
    int i = blockIdx.x * blockDim.x + threadIdx.x;
    if (i >= n8) return;
    const float4* p = (const float4*)in + (size_t)i * 2;
    float4 a = p[0], b = p[1];
    uint4 o;
    o.x = (unsigned)f2bu(a.x) | ((unsigned)f2bu(a.y) << 16);
    o.y = (unsigned)f2bu(a.z) | ((unsigned)f2bu(a.w) << 16);
    o.z = (unsigned)f2bu(b.x) | ((unsigned)f2bu(b.y) << 16);
    o.w = (unsigned)f2bu(b.z) | ((unsigned)f2bu(b.w) << 16);
    ((uint4*)out)[i] = o;
}

// ---------------- transpose f32 [R][C] -> bf16 [C][R] ----------------
__global__ void transpose_f32_to_bf16(const float* __restrict__ in, ushort_t* __restrict__ out, int R, int C) {
    __shared__ float tile[64][65];
    int bx = blockIdx.x * 64, by = blockIdx.y * 64;
    int tx = threadIdx.x & 63, ty = threadIdx.x >> 6;
#pragma unroll
    for (int i = 0; i < 64; i += 4)
        tile[ty + i][tx] = in[(size_t)(by + ty + i) * C + bx + tx];
    __syncthreads();
#pragma unroll
    for (int i = 0; i < 64; i += 4)
        out[(size_t)(bx + ty + i) * R + by + tx] = f2bu(tile[tx][ty + i]);
}

// ---------------- GEMM: C[m][n] = sum_k A[m][k]*Bt[n][k] + bias ----------------
// A: [M][K] bf16 K-major.  Bt: [N][K] bf16 K-major.  128x128 tile, BK=64, 4 waves.
__global__ __launch_bounds__(256, 2)
void gemm_bf16(const ushort_t* __restrict__ A, const ushort_t* __restrict__ Bt,
               const float* __restrict__ bias, int bias_per_row,
               ushort_t* __restrict__ outb, float* __restrict__ outf,
               int M, int N, int K, float out_scale, int do_gelu) {
    __shared__ char lds[2 * 128 * 144];   // A tile + B tile, 144B padded rows
    char* Al = lds;
    char* Bl = lds + 128 * 144;
    const int tid = threadIdx.x;
    const int l = tid & 63, wid = tid >> 6;
    const int wr = wid >> 1, wc = wid & 1;
    const int g = l >> 4, l15 = l & 15;
    const int m0 = blockIdx.x * 128, n0 = blockIdx.y * 128;

    f32x4 acc[4][4] = {};
    const int nk = K >> 6;
    const int srow = tid >> 3, sslot = tid & 7;   // staging: chunk row/slot (16B each)
    const ushort_t* Abase = A + (size_t)m0 * K + sslot * 8;
    const ushort_t* Bbase = Bt + (size_t)n0 * K + sslot * 8;

    int4 ra[4], rb[4];
#pragma unroll
    for (int i = 0; i < 4; i++) {
        ra[i] = *(const int4*)(Abase + (size_t)(srow + 32 * i) * K);
        rb[i] = *(const int4*)(Bbase + (size_t)(srow + 32 * i) * K);
    }

    for (int kt = 0; kt < nk; ++kt) {
        __syncthreads();
#pragma unroll
        for (int i = 0; i < 4; i++) {
            *(int4*)(Al + (srow + 32 * i) * 144 + sslot * 16) = ra[i];
            *(int4*)(Bl + (srow + 32 * i) * 144 + sslot * 16) = rb[i];
        }
        __syncthreads();
        if (kt + 1 < nk) {
            const ushort_t* An = Abase + (kt + 1) * 64;
            const ushort_t* Bn = Bbase + (kt + 1) * 64;
#pragma unroll
            for (int i = 0; i < 4; i++) {
                ra[i] = *(const int4*)(An + (size_t)(srow + 32 * i) * K);
                rb[i] = *(const int4*)(Bn + (size_t)(srow + 32 * i) * K);
            }
        }
#pragma unroll
        for (int ks = 0; ks < 2; ks++) {
            bf16x8 af[4];
#pragma unroll
            for (int m = 0; m < 4; m++)
                af[m] = *(const bf16x8*)(Al + (wr * 64 + m * 16 + l15) * 144 + (ks * 4 + g) * 16);
#pragma unroll
            for (int n = 0; n < 4; n++) {
                bf16x8 bfr = *(const bf16x8*)(Bl + (wc * 64 + n * 16 + l15) * 144 + (ks * 4 + g) * 16);
#pragma unroll
                for (int m = 0; m < 4; m++)
                    acc[m][n] = __builtin_amdgcn_mfma_f32_16x16x32_bf16(af[m], bfr, acc[m][n], 0, 0, 0);
            }
        }
    }
    // epilogue
#pragma unroll
    for (int m = 0; m < 4; m++) {
        int row0 = m0 + wr * 64 + m * 16 + g * 4;
#pragma unroll
        for (int n = 0; n < 4; n++) {
            int col = n0 + wc * 64 + n * 16 + l15;
            float bc = bias_per_row ? 0.f : bias[col];
#pragma unroll
            for (int jj = 0; jj < 4; jj++) {
                int row = row0 + jj;
                float v = acc[m][n][jj] + (bias_per_row ? bias[row] : bc);
                v *= out_scale;
                if (do_gelu) v = 0.5f * v * (1.f + erff(v * 0.70710678118654752f));
                size_t idx = (size_t)row * N + col;
                if (outb) outb[idx] = f2bu(v);
                else      outf[idx] = v;
            }
        }
    }
}

// ---------------- fused causal flash attention ----------------
// q,k: [4096][1024] bf16 (q pre-scaled by 0.125). vT: [1024][4096] bf16.
// Computes S^T = K*Q^T per 64-kv tile; softmax per lane (one q/lane); PV via O^T = vT * P^T.
__global__ __launch_bounds__(256)
void attn_fwd(const ushort_t* __restrict__ qg, const ushort_t* __restrict__ kg,
              const ushort_t* __restrict__ vtg, ushort_t* __restrict__ ctx) {
    __shared__ char plds[4 * 16 * 144];   // per-wave P^T staging (padded rows)
    const int tid = threadIdx.x;
    const int l = tid & 63, w = tid >> 6;
    const int g = l >> 4, l15 = l & 15;
    const int bid = blockIdx.x;
    const int QBi = bid & 31, h = (bid >> 5) & 15, b = bid >> 9;
    const int q0 = QBi * 64;
    const int qrow = b * SEQ + q0 + w * 16 + l15;
    const int q_local = w * 16 + l15;

    const ushort_t* qp = qg + (size_t)qrow * D_MODEL + h * HDIM + g * 8;
    bf16x8 qf0 = *(const bf16x8*)qp;
    bf16x8 qf1 = *(const bf16x8*)(qp + 32);

    f32x4 O[4] = {};
    float m_run = -1e30f, l_run = 0.f;
    char* pl = plds + w * (16 * 144) + l15 * 144;

    for (int t = 0; t <= QBi; ++t) {
        const int kv0 = t * 64;
        f32x4 s[4];
#pragma unroll
        for (int md = 0; md < 4; ++md) {
            const ushort_t* kp = kg + (size_t)(b * SEQ + kv0 + md * 16 + l15) * D_MODEL + h * HDIM + g * 8;
            f32x4 z = {0.f, 0.f, 0.f, 0.f};
            z = __builtin_amdgcn_mfma_f32_16x16x32_bf16(*(const bf16x8*)kp, qf0, z, 0, 0, 0);
            z = __builtin_amdgcn_mfma_f32_16x16x32_bf16(*(const bf16x8*)(kp + 32), qf1, z, 0, 0, 0);
            s[md] = z;
        }
        if (t == QBi) {
#pragma unroll
            for (int md = 0; md < 4; ++md)
#pragma unroll
                for (int jj = 0; jj < 4; jj++) {
                    int kvl = md * 16 + g * 4 + jj;
                    if (kvl > q_local) s[md][jj] = -1e30f;
                }
        }
        float pmax = -1e30f;
#pragma unroll
        for (int md = 0; md < 4; ++md)
#pragma unroll
            for (int jj = 0; jj < 4; jj++) pmax = fmaxf(pmax, s[md][jj]);
        pmax = fmaxf(pmax, __shfl_xor(pmax, 16));
        pmax = fmaxf(pmax, __shfl_xor(pmax, 32));
        float mnew = fmaxf(m_run, pmax);
        float sc = __expf(m_run - mnew);
        float rsum = 0.f;
#pragma unroll
        for (int md = 0; md < 4; ++md) {
            float p0 = __expf(s[md][0] - mnew);
            float p1 = __expf(s[md][1] - mnew);
            float p2 = __expf(s[md][2] - mnew);
            float p3 = __expf(s[md][3] - mnew);
            rsum += (p0 + p1) + (p2 + p3);
            uint2 pk;
            pk.x = (unsigned)f2bu(p0) | ((unsigned)f2bu(p1) << 16);
            pk.y = (unsigned)f2bu(p2) | ((unsigned)f2bu(p3) << 16);
            *(uint2*)(pl + (md * 16 + g * 4) * 2) = pk;
        }
        rsum += __shfl_xor(rsum, 16);
        rsum += __shfl_xor(rsum, 32);
        l_run = l_run * sc + rsum;
        m_run = mnew;
#pragma unroll
        for (int md = 0; md < 4; ++md) {
            O[md][0] *= sc; O[md][1] *= sc; O[md][2] *= sc; O[md][3] *= sc;
        }
#pragma unroll
        for (int ks = 0; ks < 2; ++ks) {
            bf16x8 pf = *(const bf16x8*)(pl + ks * 64 + g * 16);
#pragma unroll
            for (int md = 0; md < 4; ++md) {
                const ushort_t* vp = vtg + (size_t)(h * HDIM + md * 16 + l15) * NTOK + b * SEQ + kv0 + ks * 32 + g * 8;
                O[md] = __builtin_amdgcn_mfma_f32_16x16x32_bf16(*(const bf16x8*)vp, pf, O[md], 0, 0, 0);
            }
        }
    }
    float rl = 1.f / l_run;
#pragma unroll
    for (int md = 0; md < 4; ++md) {
        uint2 o;
        o.x = (unsigned)f2bu(O[md][0] * rl) | ((unsigned)f2bu(O[md][1] * rl) << 16);
        o.y = (unsigned)f2bu(O[md][2] * rl) | ((unsigned)f2bu(O[md][3] * rl) << 16);
        *(uint2*)(ctx + (size_t)qrow * D_MODEL + h * HDIM + md * 16 + g * 4) = o;
    }
}

// ---------------- fused residual + LayerNorm (1 wave / row of 1024) ----------------
__global__ __launch_bounds__(256)
void ln_kernel(const ushort_t* __restrict__ a, const ushort_t* __restrict__ resb,
               const float* __restrict__ resf,
               const float* __restrict__ gam, const float* __restrict__ bet,
               ushort_t* __restrict__ outb, float* __restrict__ outf) {
    const int w = threadIdx.x >> 6, l = threadIdx.x & 63;
    const int row = blockIdx.x * 4 + w;
    const size_t base = (size_t)row * D_MODEL + l * 16;
    float r[16];
    int4 av0 = *(const int4*)(a + base);
    int4 av1 = *(const int4*)(a + base + 8);
    const unsigned short* u0 = (const unsigned short*)&av0;
    const unsigned short* u1 = (const unsigned short*)&av1;
#pragma unroll
    for (int i = 0; i < 8; i++) { r[i] = b2f(u0[i]); r[8 + i] = b2f(u1[i]); }
    if (resf) {
        const float4* rp = (const float4*)(resf + base);
#pragma unroll
        for (int i = 0; i < 4; i++) {
            float4 f = rp[i];
            r[i * 4 + 0] += f.x; r[i * 4 + 1] += f.y; r[i * 4 + 2] += f.z; r[i * 4 + 3] += f.w;
        }
    } else {
        int4 rv0 = *(const int4*)(resb + base);
        int4 rv1 = *(const int4*)(resb + base + 8);
        const unsigned short* v0 = (const unsigned short*)&rv0;
        const unsigned short* v1 = (const unsigned short*)&rv1;
#pragma unroll
        for (int i = 0; i < 8; i++) { r[i] += b2f(v0[i]); r[8 + i] += b2f(v1[i]); }
    }
    float s = 0.f;
#pragma unroll
    for (int i = 0; i < 16; i++) s += r[i];
#pragma unroll
    for (int m = 1; m < 64; m <<= 1) s += __shfl_xor(s, m);
    float mu = s * (1.f / 1024.f);
    float v = 0.f;
#pragma unroll
    for (int i = 0; i < 16; i++) { float d = r[i] - mu; v += d * d; }
#pragma unroll
    for (int m = 1; m < 64; m <<= 1) v += __shfl_xor(v, m);
    float rstd = rsqrtf(v * (1.f / 1024.f) + 1e-5f);
    float o[16];
    const float4* gp = (const float4*)(gam + l * 16);
    const float4* bp = (const float4*)(bet + l * 16);
#pragma unroll
    for (int i = 0; i < 4; i++) {
        float4 gv = gp[i], bv = bp[i];
        o[i * 4 + 0] = (r[i * 4 + 0] - mu) * rstd * gv.x + bv.x;
        o[i * 4 + 1] = (r[i * 4 + 1] - mu) * rstd * gv.y + bv.y;
        o[i * 4 + 2] = (r[i * 4 + 2] - mu) * rstd * gv.z + bv.z;
        o[i * 4 + 3] = (r[i * 4 + 3] - mu) * rstd * gv.w + bv.w;
    }
    if (outb) {
        uint4 w0, w1;
        unsigned* pw0 = (unsigned*)&w0;
        unsigned* pw1 = (unsigned*)&w1;
#pragma unroll
        for (int i = 0; i < 4; i++) {
            pw0[i] = (unsigned)f2bu(o[i * 2]) | ((unsigned)f2bu(o[i * 2 + 1]) << 16);
            pw1[i] = (unsigned)f2bu(o[8 + i * 2]) | ((unsigned)f2bu(o[8 + i * 2 + 1]) << 16);
        }
        *(uint4*)(outb + base) = w0;
        *(uint4*)(outb + base + 8) = w1;
    } else {
        float4* op = (float4*)(outf + base);
#pragma unroll
        for (int i = 0; i < 4; i++)
            op[i] = make_float4(o[i * 4], o[i * 4 + 1], o[i * 4 + 2], o[i * 4 + 3]);
    }
}

extern "C" void kernel_launch(void* const* d_in, const int* in_sizes, int n_in,
                              void* d_out, int out_size, void* d_ws, size_t ws_size,
                              hipStream_t stream) {
    const float* x     = (const float*)d_in[0];
    const float* Wq    = (const float*)d_in[1];
    const float* bq    = (const float*)d_in[2];
    const float* Wk    = (const float*)d_in[3];
    const float* bk    = (const float*)d_in[4];
    const float* Wv    = (const float*)d_in[5];
    const float* bv    = (const float*)d_in[6];
    const float* Wo    = (const float*)d_in[7];
    const float* bo    = (const float*)d_in[8];
    const float* ln1_g = (const float*)d_in[9];
    const float* ln1_b = (const float*)d_in[10];
    const float* W1    = (const float*)d_in[11];
    const float* b1    = (const float*)d_in[12];
    const float* W2    = (const float*)d_in[13];
    const float* b2    = (const float*)d_in[14];
    const float* ln2_g = (const float*)d_in[15];
    const float* ln2_b = (const float*)d_in[16];
    float* out = (float*)d_out;

    char* ws = (char*)d_ws;
    const size_t SZ = (size_t)NTOK * D_MODEL * 2;  // 8 MB: one [4096][1024] bf16 buffer
    ushort_t* xb  = (ushort_t*)(ws + 0 * SZ);
    ushort_t* qb  = (ushort_t*)(ws + 1 * SZ);
    ushort_t* kb  = (ushort_t*)(ws + 2 * SZ);
    ushort_t* vt  = (ushort_t*)(ws + 3 * SZ);
    ushort_t* ctx = (ushort_t*)(ws + 4 * SZ);
    ushort_t* aob = (ushort_t*)(ws + 5 * SZ);
    ushort_t* hb  = (ushort_t*)(ws + 6 * SZ);
    char* wts = ws + 7 * SZ;
    ushort_t* wqt = (ushort_t*)(wts + 0x000000);
    ushort_t* wkt = (ushort_t*)(wts + 0x200000);
    ushort_t* wvt = (ushort_t*)(wts + 0x400000);
    ushort_t* wot = (ushort_t*)(wts + 0x600000);
    ushort_t* w1t = (ushort_t*)(wts + 0x800000);
    ushort_t* w2t = (ushort_t*)(wts + 0x1000000);
    // FFN buffers alias dead earlier buffers:
    ushort_t* f1b = (ushort_t*)(ws + 0 * SZ);  // 32MB spans xb,qb,kb,vt (all dead by then)
    ushort_t* f2b = (ushort_t*)(ws + 4 * SZ);  // aliases ctx (dead)
    if (ws_size < (size_t)(7 * SZ) + 0x1800000) return;

    cast_f32_to_bf16<<<2048, 256, 0, stream>>>(x, xb, NTOK * D_MODEL / 8);
    transpose_f32_to_bf16<<<dim3(16, 16), 256, 0, stream>>>(Wq, wqt, 1024, 1024);
    transpose_f32_to_bf16<<<dim3(16, 16), 256, 0, stream>>>(Wk, wkt, 1024, 1024);
    transpose_f32_to_bf16<<<dim3(16, 16), 256, 0, stream>>>(Wv, wvt, 1024, 1024);
    transpose_f32_to_bf16<<<dim3(16, 16), 256, 0, stream>>>(Wo, wot, 1024, 1024);
    transpose_f32_to_bf16<<<dim3(64, 16), 256, 0, stream>>>(W1, w1t, 1024, 4096);
    transpose_f32_to_bf16<<<dim3(16, 64), 256, 0, stream>>>(W2, w2t, 4096, 1024);

    // q scaled by 1/sqrt(64) at the source
    gemm_bf16<<<dim3(32, 8), 256, 0, stream>>>(xb, wqt, bq, 0, qb, nullptr, 4096, 1024, 1024, 0.125f, 0);
    gemm_bf16<<<dim3(32, 8), 256, 0, stream>>>(xb, wkt, bk, 0, kb, nullptr, 4096, 1024, 1024, 1.f, 0);
    // vT = Wv^T * x^T  (swapped operands -> output already transposed [1024][4096])
    gemm_bf16<<<dim3(8, 32), 256, 0, stream>>>(wvt, xb, bv, 1, vt, nullptr, 1024, 4096, 1024, 1.f, 0);

    attn_fwd<<<1024, 256, 0, stream>>>(qb, kb, vt, ctx);

    gemm_bf16<<<dim3(32, 8), 256, 0, stream>>>(ctx, wot, bo, 0, aob, nullptr, 4096, 1024, 1024, 1.f, 0);
    ln_kernel<<<1024, 256, 0, stream>>>(aob, nullptr, x, ln1_g, ln1_b, hb, nullptr);
    gemm_bf16<<<dim3(32, 32), 256, 0, stream>>>(hb, w1t, b1, 0, f1b, nullptr, 4096, 4096, 1024, 1.f, 1);
    gemm_bf16<<<dim3(32, 8), 256, 0, stream>>>(f1b, w2t, b2, 0, f2b, nullptr, 4096, 1024, 4096, 1.f, 0);
    ln_kernel<<<1024, 256, 0, stream>>>(f2b, hb, nullptr, ln2_g, ln2_b, nullptr, out);
}

// Round 6
// 647.563 us; speedup vs baseline: 1.7167x; 1.7167x over previous
//
#include <hip/hip_runtime.h>

#define D_MODEL 1024
#define SEQ 2048
#define NHEAD 16
#define HDIM 64
#define FF_DIM 4096
#define NTOK 4096  // 2 * 2048

using bf16x8 = __attribute__((ext_vector_type(8))) short;
using f32x4  = __attribute__((ext_vector_type(4))) float;
typedef unsigned short ushort_t;

__device__ __forceinline__ unsigned short f2bu(float f) {
    unsigned int u = __float_as_uint(f);
    unsigned int r = u + 0x7FFFu + ((u >> 16) & 1u);
    return (unsigned short)(r >> 16);
}
__device__ __forceinline__ float b2f(unsigned short u) {
    union { unsigned int i; float f; } x;
    x.i = ((unsigned int)u) << 16;
    return x.f;
}

// direct global -> LDS async copy, 16B per lane, wave-uniform LDS base
typedef __attribute__((address_space(1))) const unsigned int* gas_ptr;
typedef __attribute__((address_space(3))) unsigned int* las_ptr;
__device__ __forceinline__ void gload_lds16(const void* g, void* l) {
    __builtin_amdgcn_global_load_lds((gas_ptr)g, (las_ptr)l, 16, 0, 0);
}

// fast exact-enough GELU (tanh form, exp-based; |err| < 4e-4 abs)
__device__ __forceinline__ float gelu_f(float x) {
    float z = 1.59576912f * x * (1.f + 0.044715f * x * x);  // 2*0.79788456*x*(...)
    float t = __expf(z);
    // tanh(z/2)... note: using tanh(y)= (e^{2y}-1)/(e^{2y}+1) with 2y = z
    float th = (t - 1.f) / (t + 1.f);
    return 0.5f * x * (1.f + th);
}

// ---------------- cast f32 -> bf16 (8 elems / thread) ----------------
__global__ void cast_f32_to_bf16(const float* __restrict__ in, ushort_t* __restrict__ out, int n8) {
    int i = blockIdx.x * blockDim.x + threadIdx.x;
    if (i >= n8) return;
    const float4* p = (const float4*)in + (size_t)i * 2;
    float4 a = p[0], b = p[1];
    uint4 o;
    o.x = (unsigned)f2bu(a.x) | ((unsigned)f2bu(a.y) << 16);
    o.y = (unsigned)f2bu(a.z) | ((unsigned)f2bu(a.w) << 16);
    o.z = (unsigned)f2bu(b.x) | ((unsigned)f2bu(b.y) << 16);
    o.w = (unsigned)f2bu(b.z) | ((unsigned)f2bu(b.w) << 16);
    ((uint4*)out)[i] = o;
}

// ---------------- transpose f32 [R][C] -> bf16 [C][R] ----------------
__global__ void transpose_f32_to_bf16(const float* __restrict__ in, ushort_t* __restrict__ out, int R, int C) {
    __shared__ float tile[64][65];
    int bx = blockIdx.x * 64, by = blockIdx.y * 64;
    int tx = threadIdx.x & 63, ty = threadIdx.x >> 6;
#pragma unroll
    for (int i = 0; i < 64; i += 4)
        tile[ty + i][tx] = in[(size_t)(by + ty + i) * C + bx + tx];
    __syncthreads();
#pragma unroll
    for (int i = 0; i < 64; i += 4)
        out[(size_t)(bx + ty + i) * R + by + tx] = f2bu(tile[tx][ty + i]);
}

// ---------------- GEMM: C[m][n] = sum_k A[m][k]*Bt[n][k] + bias ----------------
// A: [M][K] bf16 K-major.  Bt: [N][K] bf16 K-major.  128x128 tile, BK=64, 4 waves.
// Staging: global_load_lds width=16, linear LDS [128][64] bf16 per operand (m97 structure).
__global__ __launch_bounds__(256)
void gemm_bf16(const ushort_t* __restrict__ A, const ushort_t* __restrict__ Bt,
               const float* __restrict__ bias, int bias_per_row,
               ushort_t* __restrict__ outb, float* __restrict__ outf,
               int M, int N, int K, float out_scale, int do_gelu) {
    __shared__ char lds[2 * 128 * 128];   // A tile 16KB + B tile 16KB, linear 128B rows
    char* Al = lds;
    char* Bl = lds + 128 * 128;
    const int tid = threadIdx.x;
    const int l = tid & 63, w = tid >> 6;
    const int wr = w >> 1, wc = w & 1;
    const int g = l >> 4, l15 = l & 15;
    const int m0 = blockIdx.x * 128, n0 = blockIdx.y * 128;

    f32x4 acc[4][4] = {};
    const int nk = K >> 6;
    // staging geometry: 1KB chunk = 8 rows x 64 cols(128B). wave w owns chunks w*4..w*4+3.
    const int srow = l >> 3;          // row within chunk
    const int scol = (l & 7) * 8;     // bf16 col offset (16B granule)
    const ushort_t* Ab = A + (size_t)(m0 + w * 32 + srow) * K + scol;
    const ushort_t* Bb = Bt + (size_t)(n0 + w * 32 + srow) * K + scol;

    for (int kt = 0; kt < nk; ++kt) {
        __syncthreads();   // all waves done reading previous tile
        const size_t ko = (size_t)kt * 64;
#pragma unroll
        for (int c = 0; c < 4; ++c) {
            gload_lds16(Ab + (size_t)c * 8 * K + ko, Al + (w * 4 + c) * 1024);
            gload_lds16(Bb + (size_t)c * 8 * K + ko, Bl + (w * 4 + c) * 1024);
        }
        __syncthreads();   // compiler drains vmcnt(0) before barrier -> LDS ready
#pragma unroll
        for (int ks = 0; ks < 2; ks++) {
            bf16x8 af[4];
#pragma unroll
            for (int m = 0; m < 4; m++)
                af[m] = *(const bf16x8*)(Al + (wr * 64 + m * 16 + l15) * 128 + (ks * 4 + g) * 16);
#pragma unroll
            for (int n = 0; n < 4; n++) {
                bf16x8 bfr = *(const bf16x8*)(Bl + (wc * 64 + n * 16 + l15) * 128 + (ks * 4 + g) * 16);
#pragma unroll
                for (int m = 0; m < 4; m++)
                    acc[m][n] = __builtin_amdgcn_mfma_f32_16x16x32_bf16(af[m], bfr, acc[m][n], 0, 0, 0);
            }
        }
    }
    // epilogue
#pragma unroll
    for (int m = 0; m < 4; m++) {
        int row0 = m0 + wr * 64 + m * 16 + g * 4;
#pragma unroll
        for (int n = 0; n < 4; n++) {
            int col = n0 + wc * 64 + n * 16 + l15;
            float bc = bias_per_row ? 0.f : bias[col];
#pragma unroll
            for (int jj = 0; jj < 4; jj++) {
                int row = row0 + jj;
                float v = acc[m][n][jj] + (bias_per_row ? bias[row] : bc);
                v *= out_scale;
                if (do_gelu) v = gelu_f(v);
                size_t idx = (size_t)row * N + col;
                if (outb) outb[idx] = f2bu(v);
                else      outf[idx] = v;
            }
        }
    }
}

// ---------------- fused causal flash attention ----------------
// q,k: [4096][1024] bf16 (q pre-scaled by 0.125). vT: [1024][4096] bf16.
// Computes S^T = K*Q^T per 64-kv tile; softmax per lane (one q/lane); PV via O^T = vT * P^T.
__global__ __launch_bounds__(256)
void attn_fwd(const ushort_t* __restrict__ qg, const ushort_t* __restrict__ kg,
              const ushort_t* __restrict__ vtg, ushort_t* __restrict__ ctx) {
    __shared__ char plds[4 * 16 * 144];   // per-wave P^T staging (padded rows)
    const int tid = threadIdx.x;
    const int l = tid & 63, w = tid >> 6;
    const int g = l >> 4, l15 = l & 15;
    const int bid = blockIdx.x;
    const int QBi = bid & 31, h = (bid >> 5) & 15, b = bid >> 9;
    const int q0 = QBi * 64;
    const int qrow = b * SEQ + q0 + w * 16 + l15;
    const int q_local = w * 16 + l15;

    const ushort_t* qp = qg + (size_t)qrow * D_MODEL + h * HDIM + g * 8;
    bf16x8 qf0 = *(const bf16x8*)qp;
    bf16x8 qf1 = *(const bf16x8*)(qp + 32);

    f32x4 O[4] = {};
    float m_run = -1e30f, l_run = 0.f;
    char* pl = plds + w * (16 * 144) + l15 * 144;

    for (int t = 0; t <= QBi; ++t) {
        const int kv0 = t * 64;
        f32x4 s[4];
#pragma unroll
        for (int md = 0; md < 4; ++md) {
            const ushort_t* kp = kg + (size_t)(b * SEQ + kv0 + md * 16 + l15) * D_MODEL + h * HDIM + g * 8;
            f32x4 z = {0.f, 0.f, 0.f, 0.f};
            z = __builtin_amdgcn_mfma_f32_16x16x32_bf16(*(const bf16x8*)kp, qf0, z, 0, 0, 0);
            z = __builtin_amdgcn_mfma_f32_16x16x32_bf16(*(const bf16x8*)(kp + 32), qf1, z, 0, 0, 0);
            s[md] = z;
        }
        if (t == QBi) {
#pragma unroll
            for (int md = 0; md < 4; ++md)
#pragma unroll
                for (int jj = 0; jj < 4; jj++) {
                    int kvl = md * 16 + g * 4 + jj;
                    if (kvl > q_local) s[md][jj] = -1e30f;
                }
        }
        float pmax = -1e30f;
#pragma unroll
        for (int md = 0; md < 4; ++md)
#pragma unroll
            for (int jj = 0; jj < 4; jj++) pmax = fmaxf(pmax, s[md][jj]);
        pmax = fmaxf(pmax, __shfl_xor(pmax, 16));
        pmax = fmaxf(pmax, __shfl_xor(pmax, 32));
        float mnew = fmaxf(m_run, pmax);
        float sc = __expf(m_run - mnew);
        float rsum = 0.f;
#pragma unroll
        for (int md = 0; md < 4; ++md) {
            float p0 = __expf(s[md][0] - mnew);
            float p1 = __expf(s[md][1] - mnew);
            float p2 = __expf(s[md][2] - mnew);
            float p3 = __expf(s[md][3] - mnew);
            rsum += (p0 + p1) + (p2 + p3);
            uint2 pk;
            pk.x = (unsigned)f2bu(p0) | ((unsigned)f2bu(p1) << 16);
            pk.y = (unsigned)f2bu(p2) | ((unsigned)f2bu(p3) << 16);
            *(uint2*)(pl + (md * 16 + g * 4) * 2) = pk;
        }
        rsum += __shfl_xor(rsum, 16);
        rsum += __shfl_xor(rsum, 32);
        l_run = l_run * sc + rsum;
        m_run = mnew;
#pragma unroll
        for (int md = 0; md < 4; ++md) {
            O[md][0] *= sc; O[md][1] *= sc; O[md][2] *= sc; O[md][3] *= sc;
        }
#pragma unroll
        for (int ks = 0; ks < 2; ++ks) {
            bf16x8 pf = *(const bf16x8*)(pl + ks * 64 + g * 16);
#pragma unroll
            for (int md = 0; md < 4; ++md) {
                const ushort_t* vp = vtg + (size_t)(h * HDIM + md * 16 + l15) * NTOK + b * SEQ + kv0 + ks * 32 + g * 8;
                O[md] = __builtin_amdgcn_mfma_f32_16x16x32_bf16(*(const bf16x8*)vp, pf, O[md], 0, 0, 0);
            }
        }
    }
    float rl = 1.f / l_run;
#pragma unroll
    for (int md = 0; md < 4; ++md) {
        uint2 o;
        o.x = (unsigned)f2bu(O[md][0] * rl) | ((unsigned)f2bu(O[md][1] * rl) << 16);
        o.y = (unsigned)f2bu(O[md][2] * rl) | ((unsigned)f2bu(O[md][3] * rl) << 16);
        *(uint2*)(ctx + (size_t)qrow * D_MODEL + h * HDIM + md * 16 + g * 4) = o;
    }
}

// ---------------- fused residual + LayerNorm (1 wave / row of 1024) ----------------
__global__ __launch_bounds__(256)
void ln_kernel(const ushort_t* __restrict__ a, const ushort_t* __restrict__ resb,
               const float* __restrict__ resf,
               const float* __restrict__ gam, const float* __restrict__ bet,
               ushort_t* __restrict__ outb, float* __restrict__ outf) {
    const int w = threadIdx.x >> 6, l = threadIdx.x & 63;
    const int row = blockIdx.x * 4 + w;
    const size_t base = (size_t)row * D_MODEL + l * 16;
    float r[16];
    int4 av0 = *(const int4*)(a + base);
    int4 av1 = *(const int4*)(a + base + 8);
    const unsigned short* u0 = (const unsigned short*)&av0;
    const unsigned short* u1 = (const unsigned short*)&av1;
#pragma unroll
    for (int i = 0; i < 8; i++) { r[i] = b2f(u0[i]); r[8 + i] = b2f(u1[i]); }
    if (resf) {
        const float4* rp = (const float4*)(resf + base);
#pragma unroll
        for (int i = 0; i < 4; i++) {
            float4 f = rp[i];
            r[i * 4 + 0] += f.x; r[i * 4 + 1] += f.y; r[i * 4 + 2] += f.z; r[i * 4 + 3] += f.w;
        }
    } else {
        int4 rv0 = *(const int4*)(resb + base);
        int4 rv1 = *(const int4*)(resb + base + 8);
        const unsigned short* v0 = (const unsigned short*)&rv0;
        const unsigned short* v1 = (const unsigned short*)&rv1;
#pragma unroll
        for (int i = 0; i < 8; i++) { r[i] += b2f(v0[i]); r[8 + i] += b2f(v1[i]); }
    }
    float s = 0.f;
#pragma unroll
    for (int i = 0; i < 16; i++) s += r[i];
#pragma unroll
    for (int m = 1; m < 64; m <<= 1) s += __shfl_xor(s, m);
    float mu = s * (1.f / 1024.f);
    float v = 0.f;
#pragma unroll
    for (int i = 0; i < 16; i++) { float d = r[i] - mu; v += d * d; }
#pragma unroll
    for (int m = 1; m < 64; m <<= 1) v += __shfl_xor(v, m);
    float rstd = rsqrtf(v * (1.f / 1024.f) + 1e-5f);
    float o[16];
    const float4* gp = (const float4*)(gam + l * 16);
    const float4* bp = (const float4*)(bet + l * 16);
#pragma unroll
    for (int i = 0; i < 4; i++) {
        float4 gv = gp[i], bv = bp[i];
        o[i * 4 + 0] = (r[i * 4 + 0] - mu) * rstd * gv.x + bv.x;
        o[i * 4 + 1] = (r[i * 4 + 1] - mu) * rstd * gv.y + bv.y;
        o[i * 4 + 2] = (r[i * 4 + 2] - mu) * rstd * gv.z + bv.z;
        o[i * 4 + 3] = (r[i * 4 + 3] - mu) * rstd * gv.w + bv.w;
    }
    if (outb) {
        uint4 w0, w1;
        unsigned* pw0 = (unsigned*)&w0;
        unsigned* pw1 = (unsigned*)&w1;
#pragma unroll
        for (int i = 0; i < 4; i++) {
            pw0[i] = (unsigned)f2bu(o[i * 2]) | ((unsigned)f2bu(o[i * 2 + 1]) << 16);
            pw1[i] = (unsigned)f2bu(o[8 + i * 2]) | ((unsigned)f2bu(o[8 + i * 2 + 1]) << 16);
        }
        *(uint4*)(outb + base) = w0;
        *(uint4*)(outb + base + 8) = w1;
    } else {
        float4* op = (float4*)(outf + base);
#pragma unroll
        for (int i = 0; i < 4; i++)
            op[i] = make_float4(o[i * 4], o[i * 4 + 1], o[i * 4 + 2], o[i * 4 + 3]);
    }
}

extern "C" void kernel_launch(void* const* d_in, const int* in_sizes, int n_in,
                              void* d_out, int out_size, void* d_ws, size_t ws_size,
                              hipStream_t stream) {
    const float* x     = (const float*)d_in[0];
    const float* Wq    = (const float*)d_in[1];
    const float* bq    = (const float*)d_in[2];
    const float* Wk    = (const float*)d_in[3];
    const float* bk    = (const float*)d_in[4];
    const float* Wv    = (const float*)d_in[5];
    const float* bv    = (const float*)d_in[6];
    const float* Wo    = (const float*)d_in[7];
    const float* bo    = (const float*)d_in[8];
    const float* ln1_g = (const float*)d_in[9];
    const float* ln1_b = (const float*)d_in[10];
    const float* W1    = (const float*)d_in[11];
    const float* b1    = (const float*)d_in[12];
    const float* W2    = (const float*)d_in[13];
    const float* b2    = (const float*)d_in[14];
    const float* ln2_g = (const float*)d_in[15];
    const float* ln2_b = (const float*)d_in[16];
    float* out = (float*)d_out;

    char* ws = (char*)d_ws;
    const size_t SZ = (size_t)NTOK * D_MODEL * 2;  // 8 MB: one [4096][1024] bf16 buffer
    ushort_t* xb  = (ushort_t*)(ws + 0 * SZ);
    ushort_t* qb  = (ushort_t*)(ws + 1 * SZ);
    ushort_t* kb  = (ushort_t*)(ws + 2 * SZ);
    ushort_t* vt  = (ushort_t*)(ws + 3 * SZ);
    ushort_t* ctx = (ushort_t*)(ws + 4 * SZ);
    ushort_t* aob = (ushort_t*)(ws + 5 * SZ);
    ushort_t* hb  = (ushort_t*)(ws + 6 * SZ);
    char* wts = ws + 7 * SZ;
    ushort_t* wqt = (ushort_t*)(wts + 0x000000);
    ushort_t* wkt = (ushort_t*)(wts + 0x200000);
    ushort_t* wvt = (ushort_t*)(wts + 0x400000);
    ushort_t* wot = (ushort_t*)(wts + 0x600000);
    ushort_t* w1t = (ushort_t*)(wts + 0x800000);
    ushort_t* w2t = (ushort_t*)(wts + 0x1000000);
    // FFN buffers alias dead earlier buffers:
    ushort_t* f1b = (ushort_t*)(ws + 0 * SZ);  // 32MB spans xb,qb,kb,vt (all dead by then)
    ushort_t* f2b = (ushort_t*)(ws + 4 * SZ);  // aliases ctx (dead)
    if (ws_size < (size_t)(7 * SZ) + 0x1800000) return;

    cast_f32_to_bf16<<<2048, 256, 0, stream>>>(x, xb, NTOK * D_MODEL / 8);
    transpose_f32_to_bf16<<<dim3(16, 16), 256, 0, stream>>>(Wq, wqt, 1024, 1024);
    transpose_f32_to_bf16<<<dim3(16, 16), 256, 0, stream>>>(Wk, wkt, 1024, 1024);
    transpose_f32_to_bf16<<<dim3(16, 16), 256, 0, stream>>>(Wv, wvt, 1024, 1024);
    transpose_f32_to_bf16<<<dim3(16, 16), 256, 0, stream>>>(Wo, wot, 1024, 1024);
    transpose_f32_to_bf16<<<dim3(64, 16), 256, 0, stream>>>(W1, w1t, 1024, 4096);
    transpose_f32_to_bf16<<<dim3(16, 64), 256, 0, stream>>>(W2, w2t, 4096, 1024);

    // q scaled by 1/sqrt(64) at the source
    gemm_bf16<<<dim3(32, 8), 256, 0, stream>>>(xb, wqt, bq, 0, qb, nullptr, 4096, 1024, 1024, 0.125f, 0);
    gemm_bf16<<<dim3(32, 8), 256, 0, stream>>>(xb, wkt, bk, 0, kb, nullptr, 4096, 1024, 1024, 1.f, 0);
    // vT = Wv^T * x^T  (swapped operands -> output already transposed [1024][4096])
    gemm_bf16<<<dim3(8, 32), 256, 0, stream>>>(wvt, xb, bv, 1, vt, nullptr, 1024, 4096, 1024, 1.f, 0);

    attn_fwd<<<1024, 256, 0, stream>>>(qb, kb, vt, ctx);

    gemm_bf16<<<dim3(32, 8), 256, 0, stream>>>(ctx, wot, bo, 0, aob, nullptr, 4096, 1024, 1024, 1.f, 0);
    ln_kernel<<<1024, 256, 0, stream>>>(aob, nullptr, x, ln1_g, ln1_b, hb, nullptr);
    gemm_bf16<<<dim3(32, 32), 256, 0, stream>>>(hb, w1t, b1, 0, f1b, nullptr, 4096, 4096, 1024, 1.f, 1);
    gemm_bf16<<<dim3(32, 8), 256, 0, stream>>>(f1b, w2t, b2, 0, f2b, nullptr, 4096, 1024, 4096, 1.f, 0);
    ln_kernel<<<1024, 256, 0, stream>>>(f2b, hb, nullptr, ln2_g, ln2_b, nullptr, out);
}

// Round 10
// 592.970 us; speedup vs baseline: 1.8747x; 1.0921x over previous
//
#include <hip/hip_runtime.h>

#define D_MODEL 1024
#define SEQ 2048
#define NHEAD 16
#define HDIM 64
#define FF_DIM 4096
#define NTOK 4096  // 2 * 2048

using bf16x8 = __attribute__((ext_vector_type(8))) short;
using f32x4  = __attribute__((ext_vector_type(4))) float;
typedef unsigned short ushort_t;

__device__ __forceinline__ unsigned short f2bu(float f) {
    unsigned int u = __float_as_uint(f);
    unsigned int r = u + 0x7FFFu + ((u >> 16) & 1u);
    return (unsigned short)(r >> 16);
}
__device__ __forceinline__ float b2f(unsigned short u) {
    union { unsigned int i; float f; } x;
    x.i = ((unsigned int)u) << 16;
    return x.f;
}

// direct global -> LDS async copy, 16B per lane, wave-uniform LDS base
typedef __attribute__((address_space(1))) const unsigned int* gas_ptr;
typedef __attribute__((address_space(3))) unsigned int* las_ptr;
__device__ __forceinline__ void gload_lds16(const void* g, void* l) {
    __builtin_amdgcn_global_load_lds((gas_ptr)g, (las_ptr)l, 16, 0, 0);
}

// fast exact-enough GELU (tanh form, exp-based; |err| < 4e-4 abs)
__device__ __forceinline__ float gelu_f(float x) {
    float z = 1.59576912f * x * (1.f + 0.044715f * x * x);
    float t = __expf(z);
    float th = (t - 1.f) / (t + 1.f);
    return 0.5f * x * (1.f + th);
}

// ---------------- cast f32 -> bf16 (8 elems / thread) ----------------
__global__ void cast_f32_to_bf16(const float* __restrict__ in, ushort_t* __restrict__ out, int n8) {
    int i = blockIdx.x * blockDim.x + threadIdx.x;
    if (i >= n8) return;
    const float4* p = (const float4*)in + (size_t)i * 2;
    float4 a = p[0], b = p[1];
    uint4 o;
    o.x = (unsigned)f2bu(a.x) | ((unsigned)f2bu(a.y) << 16);
    o.y = (unsigned)f2bu(a.z) | ((unsigned)f2bu(a.w) << 16);
    o.z = (unsigned)f2bu(b.x) | ((unsigned)f2bu(b.y) << 16);
    o.w = (unsigned)f2bu(b.z) | ((unsigned)f2bu(b.w) << 16);
    ((uint4*)out)[i] = o;
}

// ---------------- transpose f32 [R][C] -> bf16 [C][R] ----------------
__global__ void transpose_f32_to_bf16(const float* __restrict__ in, ushort_t* __restrict__ out, int R, int C) {
    __shared__ float tile[64][65];
    int bx = blockIdx.x * 64, by = blockIdx.y * 64;
    int tx = threadIdx.x & 63, ty = threadIdx.x >> 6;
#pragma unroll
    for (int i = 0; i < 64; i += 4)
        tile[ty + i][tx] = in[(size_t)(by + ty + i) * C + bx + tx];
    __syncthreads();
#pragma unroll
    for (int i = 0; i < 64; i += 4)
        out[(size_t)(bx + ty + i) * R + by + tx] = f2bu(tile[tx][ty + i]);
}

// ---------------- GEMM: C[m][n] = sum_k A[m][k]*Bt[n][k] + bias ----------------
// A: [M][K] bf16 K-major.  Bt: [N][K] bf16 K-major.  128x128 tile, BK=64, 4 waves.
// Staging: global_load_lds width=16, linear LDS [128][64] bf16 per operand (m97 structure).
__global__ __launch_bounds__(256)
void gemm_bf16(const ushort_t* __restrict__ A, const ushort_t* __restrict__ Bt,
               const float* __restrict__ bias, int bias_per_row,
               ushort_t* __restrict__ outb, float* __restrict__ outf,
               int M, int N, int K, float out_scale, int do_gelu) {
    __shared__ char lds[2 * 128 * 128];
    char* Al = lds;
    char* Bl = lds + 128 * 128;
    const int tid = threadIdx.x;
    const int l = tid & 63, w = tid >> 6;
    const int wr = w >> 1, wc = w & 1;
    const int g = l >> 4, l15 = l & 15;
    const int m0 = blockIdx.x * 128, n0 = blockIdx.y * 128;

    f32x4 acc[4][4] = {};
    const int nk = K >> 6;
    const int srow = l >> 3;
    const int scol = (l & 7) * 8;
    const ushort_t* Ab = A + (size_t)(m0 + w * 32 + srow) * K + scol;
    const ushort_t* Bb = Bt + (size_t)(n0 + w * 32 + srow) * K + scol;

    for (int kt = 0; kt < nk; ++kt) {
        __syncthreads();
        const size_t ko = (size_t)kt * 64;
#pragma unroll
        for (int c = 0; c < 4; ++c) {
            gload_lds16(Ab + (size_t)c * 8 * K + ko, Al + (w * 4 + c) * 1024);
            gload_lds16(Bb + (size_t)c * 8 * K + ko, Bl + (w * 4 + c) * 1024);
        }
        __syncthreads();
#pragma unroll
        for (int ks = 0; ks < 2; ks++) {
            bf16x8 af[4];
#pragma unroll
            for (int m = 0; m < 4; m++)
                af[m] = *(const bf16x8*)(Al + (wr * 64 + m * 16 + l15) * 128 + (ks * 4 + g) * 16);
#pragma unroll
            for (int n = 0; n < 4; n++) {
                bf16x8 bfr = *(const bf16x8*)(Bl + (wc * 64 + n * 16 + l15) * 128 + (ks * 4 + g) * 16);
#pragma unroll
                for (int m = 0; m < 4; m++)
                    acc[m][n] = __builtin_amdgcn_mfma_f32_16x16x32_bf16(af[m], bfr, acc[m][n], 0, 0, 0);
            }
        }
    }
#pragma unroll
    for (int m = 0; m < 4; m++) {
        int row0 = m0 + wr * 64 + m * 16 + g * 4;
#pragma unroll
        for (int n = 0; n < 4; n++) {
            int col = n0 + wc * 64 + n * 16 + l15;
            float bc = bias_per_row ? 0.f : bias[col];
#pragma unroll
            for (int jj = 0; jj < 4; jj++) {
                int row = row0 + jj;
                float v = acc[m][n][jj] + (bias_per_row ? bias[row] : bc);
                v *= out_scale;
                if (do_gelu) v = gelu_f(v);
                size_t idx = (size_t)row * N + col;
                if (outb) outb[idx] = f2bu(v);
                else      outf[idx] = v;
            }
        }
    }
}

// ---------------- fused causal flash attention (pipelined) ----------------
// q,k: [4096][1024] bf16 (q pre-scaled by 0.125). vT: [1024][4096] bf16.
// S^T = K*Q^T per 64-kv tile; softmax per lane (one q/lane); PV via O^T = vT * P^T.
// (a) XCD-aware block decode — bid&7 selects the XCD (round-robin dispatch),
//     each XCD owns heads {xcd, xcd+8} so its K/V working set (2 MB) fits its 4 MB L2.
// (b) register pipeline: V[t] issued at tile top (hides under QK+softmax);
//     K[t+1] issued right after QK MFMAs consume K[t] (hides under softmax+PV).
__global__ __launch_bounds__(256)
void attn_fwd(const ushort_t* __restrict__ qg, const ushort_t* __restrict__ kg,
              const ushort_t* __restrict__ vtg, ushort_t* __restrict__ ctx) {
    __shared__ char plds[4 * 16 * 144];   // per-wave P^T staging (padded rows)
    const int tid = threadIdx.x;
    const int l = tid & 63, w = tid >> 6;
    const int g = l >> 4, l15 = l & 15;
    const int bid = blockIdx.x;
    // XCD-aware decode: 1024 blocks, 8 XCDs, 128 slots each.
    const int xcd = bid & 7;
    const int slot = bid >> 3;            // 0..127
    const int QBi = slot & 31;
    const int grp = slot >> 5;            // 0..3
    const int h = xcd + 8 * (grp & 1);    // heads h%8==xcd stay on this XCD
    const int b = grp >> 1;
    const int q0 = QBi * 64;
    const int qrow = b * SEQ + q0 + w * 16 + l15;
    const int q_local = w * 16 + l15;

    const ushort_t* qp = qg + (size_t)qrow * D_MODEL + h * HDIM + g * 8;
    bf16x8 qf0 = *(const bf16x8*)qp;
    bf16x8 qf1 = *(const bf16x8*)(qp + 32);

    // per-lane K row base (row l15 of the head slice) and V row base
    const ushort_t* kbase = kg + ((size_t)(b * SEQ + l15) * D_MODEL) + h * HDIM + g * 8;
    const ushort_t* vbase = vtg + (size_t)(h * HDIM + l15) * NTOK + b * SEQ + g * 8;

    f32x4 O[4] = {};
    float m_run = -1e30f, l_run = 0.f;
    char* pl = plds + w * (16 * 144) + l15 * 144;

    bf16x8 kf[8];   // K[t] fragments: [md][lo/hi]
    bf16x8 vf[8];   // V[t] fragments: [md][ks]
#pragma unroll
    for (int md = 0; md < 4; ++md) {
        const ushort_t* kp = kbase + (size_t)(md * 16) * D_MODEL;
        kf[2 * md]     = *(const bf16x8*)kp;
        kf[2 * md + 1] = *(const bf16x8*)(kp + 32);
    }

    for (int t = 0; t <= QBi; ++t) {
        const int kv0 = t * 64;
        // issue V[t] loads now; they complete under QK^T + softmax
#pragma unroll
        for (int md = 0; md < 4; ++md) {
            const ushort_t* vp = vbase + (size_t)(md * 16) * NTOK + kv0;
            vf[2 * md]     = *(const bf16x8*)vp;          // ks=0
            vf[2 * md + 1] = *(const bf16x8*)(vp + 32);   // ks=1
        }
        // QK^T from prefetched K regs
        f32x4 s[4];
#pragma unroll
        for (int md = 0; md < 4; ++md) {
            f32x4 z = {0.f, 0.f, 0.f, 0.f};
            z = __builtin_amdgcn_mfma_f32_16x16x32_bf16(kf[2 * md], qf0, z, 0, 0, 0);
            z = __builtin_amdgcn_mfma_f32_16x16x32_bf16(kf[2 * md + 1], qf1, z, 0, 0, 0);
            s[md] = z;
        }
        // prefetch K[t+1]; completes under softmax + PV
        {
            const int tn = (t < QBi) ? (t + 1) : t;
#pragma unroll
            for (int md = 0; md < 4; ++md) {
                const ushort_t* kp = kbase + (size_t)(tn * 64 + md * 16) * D_MODEL;
                kf[2 * md]     = *(const bf16x8*)kp;
                kf[2 * md + 1] = *(const bf16x8*)(kp + 32);
            }
        }
        if (t == QBi) {
#pragma unroll
            for (int md = 0; md < 4; ++md)
#pragma unroll
                for (int jj = 0; jj < 4; jj++) {
                    int kvl = md * 16 + g * 4 + jj;
                    if (kvl > q_local) s[md][jj] = -1e30f;
                }
        }
        float pmax = -1e30f;
#pragma unroll
        for (int md = 0; md < 4; ++md)
#pragma unroll
            for (int jj = 0; jj < 4; jj++) pmax = fmaxf(pmax, s[md][jj]);
        pmax = fmaxf(pmax, __shfl_xor(pmax, 16));
        pmax = fmaxf(pmax, __shfl_xor(pmax, 32));
        float mnew = fmaxf(m_run, pmax);
        float sc = __expf(m_run - mnew);
        float rsum = 0.f;
#pragma unroll
        for (int md = 0; md < 4; ++md) {
            float p0 = __expf(s[md][0] - mnew);
            float p1 = __expf(s[md][1] - mnew);
            float p2 = __expf(s[md][2] - mnew);
            float p3 = __expf(s[md][3] - mnew);
            rsum += (p0 + p1) + (p2 + p3);
            uint2 pk;
            pk.x = (unsigned)f2bu(p0) | ((unsigned)f2bu(p1) << 16);
            pk.y = (unsigned)f2bu(p2) | ((unsigned)f2bu(p3) << 16);
            *(uint2*)(pl + (md * 16 + g * 4) * 2) = pk;
        }
        rsum += __shfl_xor(rsum, 16);
        rsum += __shfl_xor(rsum, 32);
        l_run = l_run * sc + rsum;
        m_run = mnew;
#pragma unroll
        for (int md = 0; md < 4; ++md) {
            O[md][0] *= sc; O[md][1] *= sc; O[md][2] *= sc; O[md][3] *= sc;
        }
#pragma unroll
        for (int ks = 0; ks < 2; ++ks) {
            bf16x8 pf = *(const bf16x8*)(pl + ks * 64 + g * 16);
#pragma unroll
            for (int md = 0; md < 4; ++md)
                O[md] = __builtin_amdgcn_mfma_f32_16x16x32_bf16(vf[2 * md + ks], pf, O[md], 0, 0, 0);
        }
    }
    float rl = 1.f / l_run;
#pragma unroll
    for (int md = 0; md < 4; ++md) {
        uint2 o;
        o.x = (unsigned)f2bu(O[md][0] * rl) | ((unsigned)f2bu(O[md][1] * rl) << 16);
        o.y = (unsigned)f2bu(O[md][2] * rl) | ((unsigned)f2bu(O[md][3] * rl) << 16);
        *(uint2*)(ctx + (size_t)qrow * D_MODEL + h * HDIM + md * 16 + g * 4) = o;
    }
}

// ---------------- fused residual + LayerNorm (1 wave / row of 1024) ----------------
__global__ __launch_bounds__(256)
void ln_kernel(const ushort_t* __restrict__ a, const ushort_t* __restrict__ resb,
               const float* __restrict__ resf,
               const float* __restrict__ gam, const float* __restrict__ bet,
               ushort_t* __restrict__ outb, float* __restrict__ outf) {
    const int w = threadIdx.x >> 6, l = threadIdx.x & 63;
    const int row = blockIdx.x * 4 + w;
    const size_t base = (size_t)row * D_MODEL + l * 16;
    float r[16];
    int4 av0 = *(const int4*)(a + base);
    int4 av1 = *(const int4*)(a + base + 8);
    const unsigned short* u0 = (const unsigned short*)&av0;
    const unsigned short* u1 = (const unsigned short*)&av1;
#pragma unroll
    for (int i = 0; i < 8; i++) { r[i] = b2f(u0[i]); r[8 + i] = b2f(u1[i]); }
    if (resf) {
        const float4* rp = (const float4*)(resf + base);
#pragma unroll
        for (int i = 0; i < 4; i++) {
            float4 f = rp[i];
            r[i * 4 + 0] += f.x; r[i * 4 + 1] += f.y; r[i * 4 + 2] += f.z; r[i * 4 + 3] += f.w;
        }
    } else {
        int4 rv0 = *(const int4*)(resb + base);
        int4 rv1 = *(const int4*)(resb + base + 8);
        const unsigned short* v0 = (const unsigned short*)&rv0;
        const unsigned short* v1 = (const unsigned short*)&rv1;
#pragma unroll
        for (int i = 0; i < 8; i++) { r[i] += b2f(v0[i]); r[8 + i] += b2f(v1[i]); }
    }
    float s = 0.f;
#pragma unroll
    for (int i = 0; i < 16; i++) s += r[i];
#pragma unroll
    for (int m = 1; m < 64; m <<= 1) s += __shfl_xor(s, m);
    float mu = s * (1.f / 1024.f);
    float v = 0.f;
#pragma unroll
    for (int i = 0; i < 16; i++) { float d = r[i] - mu; v += d * d; }
#pragma unroll
    for (int m = 1; m < 64; m <<= 1) v += __shfl_xor(v, m);
    float rstd = rsqrtf(v * (1.f / 1024.f) + 1e-5f);
    float o[16];
    const float4* gp = (const float4*)(gam + l * 16);
    const float4* bp = (const float4*)(bet + l * 16);
#pragma unroll
    for (int i = 0; i < 4; i++) {
        float4 gv = gp[i], bv = bp[i];
        o[i * 4 + 0] = (r[i * 4 + 0] - mu) * rstd * gv.x + bv.x;
        o[i * 4 + 1] = (r[i * 4 + 1] - mu) * rstd * gv.y + bv.y;
        o[i * 4 + 2] = (r[i * 4 + 2] - mu) * rstd * gv.z + bv.z;
        o[i * 4 + 3] = (r[i * 4 + 3] - mu) * rstd * gv.w + bv.w;
    }
    if (outb) {
        uint4 w0, w1;
        unsigned* pw0 = (unsigned*)&w0;
        unsigned* pw1 = (unsigned*)&w1;
#pragma unroll
        for (int i = 0; i < 4; i++) {
            pw0[i] = (unsigned)f2bu(o[i * 2]) | ((unsigned)f2bu(o[i * 2 + 1]) << 16);
            pw1[i] = (unsigned)f2bu(o[8 + i * 2]) | ((unsigned)f2bu(o[8 + i * 2 + 1]) << 16);
        }
        *(uint4*)(outb + base) = w0;
        *(uint4*)(outb + base + 8) = w1;
    } else {
        float4* op = (float4*)(outf + base);
#pragma unroll
        for (int i = 0; i < 4; i++)
            op[i] = make_float4(o[i * 4], o[i * 4 + 1], o[i * 4 + 2], o[i * 4 + 3]);
    }
}

extern "C" void kernel_launch(void* const* d_in, const int* in_sizes, int n_in,
                              void* d_out, int out_size, void* d_ws, size_t ws_size,
                              hipStream_t stream) {
    const float* x     = (const float*)d_in[0];
    const float* Wq    = (const float*)d_in[1];
    const float* bq    = (const float*)d_in[2];
    const float* Wk    = (const float*)d_in[3];
    const float* bk    = (const float*)d_in[4];
    const float* Wv    = (const float*)d_in[5];
    const float* bv    = (const float*)d_in[6];
    const float* Wo    = (const float*)d_in[7];
    const float* bo    = (const float*)d_in[8];
    const float* ln1_g = (const float*)d_in[9];
    const float* ln1_b = (const float*)d_in[10];
    const float* W1    = (const float*)d_in[11];
    const float* b1    = (const float*)d_in[12];
    const float* W2    = (const float*)d_in[13];
    const float* b2    = (const float*)d_in[14];
    const float* ln2_g = (const float*)d_in[15];
    const float* ln2_b = (const float*)d_in[16];
    float* out = (float*)d_out;

    char* ws = (char*)d_ws;
    const size_t SZ = (size_t)NTOK * D_MODEL * 2;  // 8 MB: one [4096][1024] bf16 buffer
    ushort_t* xb  = (ushort_t*)(ws + 0 * SZ);
    ushort_t* qb  = (ushort_t*)(ws + 1 * SZ);
    ushort_t* kb  = (ushort_t*)(ws + 2 * SZ);
    ushort_t* vt  = (ushort_t*)(ws + 3 * SZ);
    ushort_t* ctx = (ushort_t*)(ws + 4 * SZ);
    ushort_t* aob = (ushort_t*)(ws + 5 * SZ);
    ushort_t* hb  = (ushort_t*)(ws + 6 * SZ);
    char* wts = ws + 7 * SZ;
    ushort_t* wqt = (ushort_t*)(wts + 0x000000);
    ushort_t* wkt = (ushort_t*)(wts + 0x200000);
    ushort_t* wvt = (ushort_t*)(wts + 0x400000);
    ushort_t* wot = (ushort_t*)(wts + 0x600000);
    ushort_t* w1t = (ushort_t*)(wts + 0x800000);
    ushort_t* w2t = (ushort_t*)(wts + 0x1000000);
    ushort_t* f1b = (ushort_t*)(ws + 0 * SZ);  // 32MB spans xb,qb,kb,vt (all dead by then)
    ushort_t* f2b = (ushort_t*)(ws + 4 * SZ);  // aliases ctx (dead)
    if (ws_size < (size_t)(7 * SZ) + 0x1800000) return;

    cast_f32_to_bf16<<<2048, 256, 0, stream>>>(x, xb, NTOK * D_MODEL / 8);
    transpose_f32_to_bf16<<<dim3(16, 16), 256, 0, stream>>>(Wq, wqt, 1024, 1024);
    transpose_f32_to_bf16<<<dim3(16, 16), 256, 0, stream>>>(Wk, wkt, 1024, 1024);
    transpose_f32_to_bf16<<<dim3(16, 16), 256, 0, stream>>>(Wv, wvt, 1024, 1024);
    transpose_f32_to_bf16<<<dim3(16, 16), 256, 0, stream>>>(Wo, wot, 1024, 1024);
    transpose_f32_to_bf16<<<dim3(64, 16), 256, 0, stream>>>(W1, w1t, 1024, 4096);
    transpose_f32_to_bf16<<<dim3(16, 64), 256, 0, stream>>>(W2, w2t, 4096, 1024);

    gemm_bf16<<<dim3(32, 8), 256, 0, stream>>>(xb, wqt, bq, 0, qb, nullptr, 4096, 1024, 1024, 0.125f, 0);
    gemm_bf16<<<dim3(32, 8), 256, 0, stream>>>(xb, wkt, bk, 0, kb, nullptr, 4096, 1024, 1024, 1.f, 0);
    gemm_bf16<<<dim3(8, 32), 256, 0, stream>>>(wvt, xb, bv, 1, vt, nullptr, 1024, 4096, 1024, 1.f, 0);

    attn_fwd<<<1024, 256, 0, stream>>>(qb, kb, vt, ctx);

    gemm_bf16<<<dim3(32, 8), 256, 0, stream>>>(ctx, wot, bo, 0, aob, nullptr, 4096, 1024, 1024, 1.f, 0);
    ln_kernel<<<1024, 256, 0, stream>>>(aob, nullptr, x, ln1_g, ln1_b, hb, nullptr);
    gemm_bf16<<<dim3(32, 32), 256, 0, stream>>>(hb, w1t, b1, 0, f1b, nullptr, 4096, 4096, 1024, 1.f, 1);
    gemm_bf16<<<dim3(32, 8), 256, 0, stream>>>(f1b, w2t, b2, 0, f2b, nullptr, 4096, 1024, 4096, 1.f, 0);
    ln_kernel<<<1024, 256, 0, stream>>>(f2b, hb, nullptr, ln2_g, ln2_b, nullptr, out);
}

// Round 12
// 524.499 us; speedup vs baseline: 2.1195x; 1.1305x over previous
//
#include <hip/hip_runtime.h>

#define D_MODEL 1024
#define SEQ 2048
#define NHEAD 16
#define HDIM 64
#define FF_DIM 4096
#define NTOK 4096  // 2 * 2048

using bf16x8 = __attribute__((ext_vector_type(8))) short;
using f32x4  = __attribute__((ext_vector_type(4))) float;
typedef unsigned short ushort_t;

__device__ __forceinline__ unsigned short f2bu(float f) {
    unsigned int u = __float_as_uint(f);
    unsigned int r = u + 0x7FFFu + ((u >> 16) & 1u);
    return (unsigned short)(r >> 16);
}
__device__ __forceinline__ float b2f(unsigned short u) {
    union { unsigned int i; float f; } x;
    x.i = ((unsigned int)u) << 16;
    return x.f;
}

// direct global -> LDS async copy, 16B per lane, wave-uniform LDS base
typedef __attribute__((address_space(1))) const unsigned int* gas_ptr;
typedef __attribute__((address_space(3))) unsigned int* las_ptr;
__device__ __forceinline__ void gload_lds16(const void* g, void* l) {
    __builtin_amdgcn_global_load_lds((gas_ptr)g, (las_ptr)l, 16, 0, 0);
}

// fast exact-enough GELU (tanh form, exp-based; |err| < 4e-4 abs)
__device__ __forceinline__ float gelu_f(float x) {
    float z = 1.59576912f * x * (1.f + 0.044715f * x * x);
    float t = __expf(z);
    float th = (t - 1.f) / (t + 1.f);
    return 0.5f * x * (1.f + th);
}

// ---------------- cast f32 -> bf16 (8 elems / thread) ----------------
__global__ void cast_f32_to_bf16(const float* __restrict__ in, ushort_t* __restrict__ out, int n8) {
    int i = blockIdx.x * blockDim.x + threadIdx.x;
    if (i >= n8) return;
    const float4* p = (const float4*)in + (size_t)i * 2;
    float4 a = p[0], b = p[1];
    uint4 o;
    o.x = (unsigned)f2bu(a.x) | ((unsigned)f2bu(a.y) << 16);
    o.y = (unsigned)f2bu(a.z) | ((unsigned)f2bu(a.w) << 16);
    o.z = (unsigned)f2bu(b.x) | ((unsigned)f2bu(b.y) << 16);
    o.w = (unsigned)f2bu(b.z) | ((unsigned)f2bu(b.w) << 16);
    ((uint4*)out)[i] = o;
}

// ---------------- transpose f32 [R][C] -> bf16 [C][R] ----------------
__global__ void transpose_f32_to_bf16(const float* __restrict__ in, ushort_t* __restrict__ out, int R, int C) {
    __shared__ float tile[64][65];
    int bx = blockIdx.x * 64, by = blockIdx.y * 64;
    int tx = threadIdx.x & 63, ty = threadIdx.x >> 6;
#pragma unroll
    for (int i = 0; i < 64; i += 4)
        tile[ty + i][tx] = in[(size_t)(by + ty + i) * C + bx + tx];
    __syncthreads();
#pragma unroll
    for (int i = 0; i < 64; i += 4)
        out[(size_t)(bx + ty + i) * R + by + tx] = f2bu(tile[tx][ty + i]);
}

// ---------------- GEMM: C[m][n] = sum_k A[m][k]*Bt[n][k] + bias ----------------
// A: [M][K] bf16 K-major.  Bt: [N][K] bf16 K-major.  128xBN tile, BK=64, 4 waves (2x2).
// BN=128 for big-N GEMMs; BN=64 for N/M=1024 GEMMs so grid >= 512 blocks (2 blocks/CU
// co-residency overlaps the 2-barrier staging stalls; LDS 24KB allows 6/CU).
template<int BN>
__global__ __launch_bounds__(256)
void gemm_bf16(const ushort_t* __restrict__ A, const ushort_t* __restrict__ Bt,
               const float* __restrict__ bias, int bias_per_row,
               ushort_t* __restrict__ outb, float* __restrict__ outf,
               int M, int N, int K, float out_scale, int do_gelu) {
    constexpr int NB  = BN / 32;   // 16-col frags per wave
    constexpr int BCH = BN / 32;   // 1KB B-chunks per wave
    __shared__ char lds[(128 + BN) * 128];
    char* Al = lds;
    char* Bl = lds + 128 * 128;
    const int tid = threadIdx.x;
    const int l = tid & 63, w = tid >> 6;
    const int wr = w >> 1, wc = w & 1;
    const int g = l >> 4, l15 = l & 15;
    const int m0 = blockIdx.x * 128, n0 = blockIdx.y * BN;

    f32x4 acc[4][NB] = {};
    const int nk = K >> 6;
    const int srow = l >> 3;          // row within 8-row chunk
    const int scol = (l & 7) * 8;     // bf16 col offset (16B granule)
    const ushort_t* Ab = A + (size_t)(m0 + w * 32 + srow) * K + scol;
    const ushort_t* Bb = Bt + (size_t)(n0 + w * (BN / 4) + srow) * K + scol;

    for (int kt = 0; kt < nk; ++kt) {
        __syncthreads();
        const size_t ko = (size_t)kt * 64;
#pragma unroll
        for (int c = 0; c < 4; ++c)
            gload_lds16(Ab + (size_t)c * 8 * K + ko, Al + (w * 4 + c) * 1024);
#pragma unroll
        for (int c = 0; c < BCH; ++c)
            gload_lds16(Bb + (size_t)c * 8 * K + ko, Bl + (w * BCH + c) * 1024);
        __syncthreads();
#pragma unroll
        for (int ks = 0; ks < 2; ks++) {
            bf16x8 af[4];
#pragma unroll
            for (int m = 0; m < 4; m++)
                af[m] = *(const bf16x8*)(Al + (wr * 64 + m * 16 + l15) * 128 + (ks * 4 + g) * 16);
#pragma unroll
            for (int n = 0; n < NB; n++) {
                bf16x8 bfr = *(const bf16x8*)(Bl + (wc * (BN / 2) + n * 16 + l15) * 128 + (ks * 4 + g) * 16);
#pragma unroll
                for (int m = 0; m < 4; m++)
                    acc[m][n] = __builtin_amdgcn_mfma_f32_16x16x32_bf16(af[m], bfr, acc[m][n], 0, 0, 0);
            }
        }
    }
#pragma unroll
    for (int m = 0; m < 4; m++) {
        int row0 = m0 + wr * 64 + m * 16 + g * 4;
#pragma unroll
        for (int n = 0; n < NB; n++) {
            int col = n0 + wc * (BN / 2) + n * 16 + l15;
            float bc = bias_per_row ? 0.f : bias[col];
#pragma unroll
            for (int jj = 0; jj < 4; jj++) {
                int row = row0 + jj;
                float v = acc[m][n][jj] + (bias_per_row ? bias[row] : bc);
                v *= out_scale;
                if (do_gelu) v = gelu_f(v);
                size_t idx = (size_t)row * N + col;
                if (outb) outb[idx] = f2bu(v);
                else      outf[idx] = v;
            }
        }
    }
}

// ---------------- fused causal flash attention (pipelined + balanced) ----------------
// q,k: [4096][1024] bf16 (q pre-scaled by 0.125). vT: [1024][4096] bf16.
// S^T = K*Q^T per 64-kv tile; softmax per lane (one q/lane); PV via O^T = vT * P^T.
// (a) XCD-aware decode: bid&7 = XCD; heads h%8==xcd stay on one XCD (K/V L2-resident).
// (b) register pipeline: V[t] at tile top (hides under QK+softmax); K[t+1] after QK (hides under softmax+PV).
// (c) causal load balance: each block handles complementary q-tiles {p, 31-p} = 33 tile-units, flat makespan.
__global__ __launch_bounds__(256)
void attn_fwd(const ushort_t* __restrict__ qg, const ushort_t* __restrict__ kg,
              const ushort_t* __restrict__ vtg, ushort_t* __restrict__ ctx) {
    __shared__ char plds[4 * 16 * 144];   // per-wave P^T staging (padded rows)
    const int tid = threadIdx.x;
    const int l = tid & 63, w = tid >> 6;
    const int g = l >> 4, l15 = l & 15;
    const int bid = blockIdx.x;
    // 512 blocks: 8 XCDs x 64 slots; slot = (pair, grp)
    const int xcd = bid & 7;
    const int slot = bid >> 3;            // 0..63
    const int p = slot & 15;              // pair index
    const int grp = slot >> 4;            // 0..3
    const int h = xcd + 8 * (grp & 1);    // heads h%8==xcd stay on this XCD
    const int b = grp >> 1;
    const int q_local = w * 16 + l15;

    const ushort_t* kbase = kg + ((size_t)(b * SEQ + l15) * D_MODEL) + h * HDIM + g * 8;
    const ushort_t* vbase = vtg + (size_t)(h * HDIM + l15) * NTOK + b * SEQ + g * 8;
    char* pl = plds + w * (16 * 144) + l15 * 144;

    bf16x8 kf[8];   // K[t] fragments
    bf16x8 vf[8];   // V[t] fragments

#pragma unroll
    for (int phase = 0; phase < 2; ++phase) {
        const int QBi = phase ? (31 - p) : p;
        const int qrow = b * SEQ + QBi * 64 + w * 16 + l15;

        const ushort_t* qp = qg + (size_t)qrow * D_MODEL + h * HDIM + g * 8;
        bf16x8 qf0 = *(const bf16x8*)qp;
        bf16x8 qf1 = *(const bf16x8*)(qp + 32);

        f32x4 O[4] = {};
        float m_run = -1e30f, l_run = 0.f;

#pragma unroll
        for (int md = 0; md < 4; ++md) {
            const ushort_t* kp = kbase + (size_t)(md * 16) * D_MODEL;
            kf[2 * md]     = *(const bf16x8*)kp;
            kf[2 * md + 1] = *(const bf16x8*)(kp + 32);
        }

        for (int t = 0; t <= QBi; ++t) {
            const int kv0 = t * 64;
            // issue V[t] loads now; they complete under QK^T + softmax
#pragma unroll
            for (int md = 0; md < 4; ++md) {
                const ushort_t* vp = vbase + (size_t)(md * 16) * NTOK + kv0;
                vf[2 * md]     = *(const bf16x8*)vp;
                vf[2 * md + 1] = *(const bf16x8*)(vp + 32);
            }
            // QK^T from prefetched K regs
            f32x4 s[4];
#pragma unroll
            for (int md = 0; md < 4; ++md) {
                f32x4 z = {0.f, 0.f, 0.f, 0.f};
                z = __builtin_amdgcn_mfma_f32_16x16x32_bf16(kf[2 * md], qf0, z, 0, 0, 0);
                z = __builtin_amdgcn_mfma_f32_16x16x32_bf16(kf[2 * md + 1], qf1, z, 0, 0, 0);
                s[md] = z;
            }
            // prefetch K[t+1]; completes under softmax + PV
            {
                const int tn = (t < QBi) ? (t + 1) : t;
#pragma unroll
                for (int md = 0; md < 4; ++md) {
                    const ushort_t* kp = kbase + (size_t)(tn * 64 + md * 16) * D_MODEL;
                    kf[2 * md]     = *(const bf16x8*)kp;
                    kf[2 * md + 1] = *(const bf16x8*)(kp + 32);
                }
            }
            if (t == QBi) {
#pragma unroll
                for (int md = 0; md < 4; ++md)
#pragma unroll
                    for (int jj = 0; jj < 4; jj++) {
                        int kvl = md * 16 + g * 4 + jj;
                        if (kvl > q_local) s[md][jj] = -1e30f;
                    }
            }
            float pmax = -1e30f;
#pragma unroll
            for (int md = 0; md < 4; ++md)
#pragma unroll
                for (int jj = 0; jj < 4; jj++) pmax = fmaxf(pmax, s[md][jj]);
            pmax = fmaxf(pmax, __shfl_xor(pmax, 16));
            pmax = fmaxf(pmax, __shfl_xor(pmax, 32));
            float mnew = fmaxf(m_run, pmax);
            float sc = __expf(m_run - mnew);
            float rsum = 0.f;
#pragma unroll
            for (int md = 0; md < 4; ++md) {
                float p0 = __expf(s[md][0] - mnew);
                float p1 = __expf(s[md][1] - mnew);
                float p2 = __expf(s[md][2] - mnew);
                float p3 = __expf(s[md][3] - mnew);
                rsum += (p0 + p1) + (p2 + p3);
                uint2 pk;
                pk.x = (unsigned)f2bu(p0) | ((unsigned)f2bu(p1) << 16);
                pk.y = (unsigned)f2bu(p2) | ((unsigned)f2bu(p3) << 16);
                *(uint2*)(pl + (md * 16 + g * 4) * 2) = pk;
            }
            rsum += __shfl_xor(rsum, 16);
            rsum += __shfl_xor(rsum, 32);
            l_run = l_run * sc + rsum;
            m_run = mnew;
#pragma unroll
            for (int md = 0; md < 4; ++md) {
                O[md][0] *= sc; O[md][1] *= sc; O[md][2] *= sc; O[md][3] *= sc;
            }
#pragma unroll
            for (int ks = 0; ks < 2; ++ks) {
                bf16x8 pf = *(const bf16x8*)(pl + ks * 64 + g * 16);
#pragma unroll
                for (int md = 0; md < 4; ++md)
                    O[md] = __builtin_amdgcn_mfma_f32_16x16x32_bf16(vf[2 * md + ks], pf, O[md], 0, 0, 0);
            }
        }
        float rl = 1.f / l_run;
#pragma unroll
        for (int md = 0; md < 4; ++md) {
            uint2 o;
            o.x = (unsigned)f2bu(O[md][0] * rl) | ((unsigned)f2bu(O[md][1] * rl) << 16);
            o.y = (unsigned)f2bu(O[md][2] * rl) | ((unsigned)f2bu(O[md][3] * rl) << 16);
            *(uint2*)(ctx + (size_t)qrow * D_MODEL + h * HDIM + md * 16 + g * 4) = o;
        }
    }
}

// ---------------- fused residual + LayerNorm (1 wave / row of 1024) ----------------
__global__ __launch_bounds__(256)
void ln_kernel(const ushort_t* __restrict__ a, const ushort_t* __restrict__ resb,
               const float* __restrict__ resf,
               const float* __restrict__ gam, const float* __restrict__ bet,
               ushort_t* __restrict__ outb, float* __restrict__ outf) {
    const int w = threadIdx.x >> 6, l = threadIdx.x & 63;
    const int row = blockIdx.x * 4 + w;
    const size_t base = (size_t)row * D_MODEL + l * 16;
    float r[16];
    int4 av0 = *(const int4*)(a + base);
    int4 av1 = *(const int4*)(a + base + 8);
    const unsigned short* u0 = (const unsigned short*)&av0;
    const unsigned short* u1 = (const unsigned short*)&av1;
#pragma unroll
    for (int i = 0; i < 8; i++) { r[i] = b2f(u0[i]); r[8 + i] = b2f(u1[i]); }
    if (resf) {
        const float4* rp = (const float4*)(resf + base);
#pragma unroll
        for (int i = 0; i < 4; i++) {
            float4 f = rp[i];
            r[i * 4 + 0] += f.x; r[i * 4 + 1] += f.y; r[i * 4 + 2] += f.z; r[i * 4 + 3] += f.w;
        }
    } else {
        int4 rv0 = *(const int4*)(resb + base);
        int4 rv1 = *(const int4*)(resb + base + 8);
        const unsigned short* v0 = (const unsigned short*)&rv0;
        const unsigned short* v1 = (const unsigned short*)&rv1;
#pragma unroll
        for (int i = 0; i < 8; i++) { r[i] += b2f(v0[i]); r[8 + i] += b2f(v1[i]); }
    }
    float s = 0.f;
#pragma unroll
    for (int i = 0; i < 16; i++) s += r[i];
#pragma unroll
    for (int m = 1; m < 64; m <<= 1) s += __shfl_xor(s, m);
    float mu = s * (1.f / 1024.f);
    float v = 0.f;
#pragma unroll
    for (int i = 0; i < 16; i++) { float d = r[i] - mu; v += d * d; }
#pragma unroll
    for (int m = 1; m < 64; m <<= 1) v += __shfl_xor(v, m);
    float rstd = rsqrtf(v * (1.f / 1024.f) + 1e-5f);
    float o[16];
    const float4* gp = (const float4*)(gam + l * 16);
    const float4* bp = (const float4*)(bet + l * 16);
#pragma unroll
    for (int i = 0; i < 4; i++) {
        float4 gv = gp[i], bv = bp[i];
        o[i * 4 + 0] = (r[i * 4 + 0] - mu) * rstd * gv.x + bv.x;
        o[i * 4 + 1] = (r[i * 4 + 1] - mu) * rstd * gv.y + bv.y;
        o[i * 4 + 2] = (r[i * 4 + 2] - mu) * rstd * gv.z + bv.z;
        o[i * 4 + 3] = (r[i * 4 + 3] - mu) * rstd * gv.w + bv.w;
    }
    if (outb) {
        uint4 w0, w1;
        unsigned* pw0 = (unsigned*)&w0;
        unsigned* pw1 = (unsigned*)&w1;
#pragma unroll
        for (int i = 0; i < 4; i++) {
            pw0[i] = (unsigned)f2bu(o[i * 2]) | ((unsigned)f2bu(o[i * 2 + 1]) << 16);
            pw1[i] = (unsigned)f2bu(o[8 + i * 2]) | ((unsigned)f2bu(o[8 + i * 2 + 1]) << 16);
        }
        *(uint4*)(outb + base) = w0;
        *(uint4*)(outb + base + 8) = w1;
    } else {
        float4* op = (float4*)(outf + base);
#pragma unroll
        for (int i = 0; i < 4; i++)
            op[i] = make_float4(o[i * 4], o[i * 4 + 1], o[i * 4 + 2], o[i * 4 + 3]);
    }
}

extern "C" void kernel_launch(void* const* d_in, const int* in_sizes, int n_in,
                              void* d_out, int out_size, void* d_ws, size_t ws_size,
                              hipStream_t stream) {
    const float* x     = (const float*)d_in[0];
    const float* Wq    = (const float*)d_in[1];
    const float* bq    = (const float*)d_in[2];
    const float* Wk    = (const float*)d_in[3];
    const float* bk    = (const float*)d_in[4];
    const float* Wv    = (const float*)d_in[5];
    const float* bv    = (const float*)d_in[6];
    const float* Wo    = (const float*)d_in[7];
    const float* bo    = (const float*)d_in[8];
    const float* ln1_g = (const float*)d_in[9];
    const float* ln1_b = (const float*)d_in[10];
    const float* W1    = (const float*)d_in[11];
    const float* b1    = (const float*)d_in[12];
    const float* W2    = (const float*)d_in[13];
    const float* b2    = (const float*)d_in[14];
    const float* ln2_g = (const float*)d_in[15];
    const float* ln2_b = (const float*)d_in[16];
    float* out = (float*)d_out;

    char* ws = (char*)d_ws;
    const size_t SZ = (size_t)NTOK * D_MODEL * 2;  // 8 MB: one [4096][1024] bf16 buffer
    ushort_t* xb  = (ushort_t*)(ws + 0 * SZ);
    ushort_t* qb  = (ushort_t*)(ws + 1 * SZ);
    ushort_t* kb  = (ushort_t*)(ws + 2 * SZ);
    ushort_t* vt  = (ushort_t*)(ws + 3 * SZ);
    ushort_t* ctx = (ushort_t*)(ws + 4 * SZ);
    ushort_t* aob = (ushort_t*)(ws + 5 * SZ);
    ushort_t* hb  = (ushort_t*)(ws + 6 * SZ);
    char* wts = ws + 7 * SZ;
    ushort_t* wqt = (ushort_t*)(wts + 0x000000);
    ushort_t* wkt = (ushort_t*)(wts + 0x200000);
    ushort_t* wvt = (ushort_t*)(wts + 0x400000);
    ushort_t* wot = (ushort_t*)(wts + 0x600000);
    ushort_t* w1t = (ushort_t*)(wts + 0x800000);
    ushort_t* w2t = (ushort_t*)(wts + 0x1000000);
    ushort_t* f1b = (ushort_t*)(ws + 0 * SZ);  // 32MB spans xb,qb,kb,vt (all dead by then)
    ushort_t* f2b = (ushort_t*)(ws + 4 * SZ);  // aliases ctx (dead)
    if (ws_size < (size_t)(7 * SZ) + 0x1800000) return;

    cast_f32_to_bf16<<<2048, 256, 0, stream>>>(x, xb, NTOK * D_MODEL / 8);
    transpose_f32_to_bf16<<<dim3(16, 16), 256, 0, stream>>>(Wq, wqt, 1024, 1024);
    transpose_f32_to_bf16<<<dim3(16, 16), 256, 0, stream>>>(Wk, wkt, 1024, 1024);
    transpose_f32_to_bf16<<<dim3(16, 16), 256, 0, stream>>>(Wv, wvt, 1024, 1024);
    transpose_f32_to_bf16<<<dim3(16, 16), 256, 0, stream>>>(Wo, wot, 1024, 1024);
    transpose_f32_to_bf16<<<dim3(64, 16), 256, 0, stream>>>(W1, w1t, 1024, 4096);
    transpose_f32_to_bf16<<<dim3(16, 64), 256, 0, stream>>>(W2, w2t, 4096, 1024);

    // N=1024 / M=1024 GEMMs use BN=64 -> >=512-block grids (2 blocks/CU)
    gemm_bf16<64><<<dim3(32, 16), 256, 0, stream>>>(xb, wqt, bq, 0, qb, nullptr, 4096, 1024, 1024, 0.125f, 0);
    gemm_bf16<64><<<dim3(32, 16), 256, 0, stream>>>(xb, wkt, bk, 0, kb, nullptr, 4096, 1024, 1024, 1.f, 0);
    gemm_bf16<64><<<dim3(8, 64), 256, 0, stream>>>(wvt, xb, bv, 1, vt, nullptr, 1024, 4096, 1024, 1.f, 0);

    attn_fwd<<<512, 256, 0, stream>>>(qb, kb, vt, ctx);

    gemm_bf16<64><<<dim3(32, 16), 256, 0, stream>>>(ctx, wot, bo, 0, aob, nullptr, 4096, 1024, 1024, 1.f, 0);
    ln_kernel<<<1024, 256, 0, stream>>>(aob, nullptr, x, ln1_g, ln1_b, hb, nullptr);
    gemm_bf16<128><<<dim3(32, 32), 256, 0, stream>>>(hb, w1t, b1, 0, f1b, nullptr, 4096, 4096, 1024, 1.f, 1);
    gemm_bf16<64><<<dim3(32, 16), 256, 0, stream>>>(f1b, w2t, b2, 0, f2b, nullptr, 4096, 1024, 4096, 1.f, 0);
    ln_kernel<<<1024, 256, 0, stream>>>(f2b, hb, nullptr, ln2_g, ln2_b, nullptr, out);
}